// Round 9
// baseline (228.798 us; speedup 1.0000x reference)
//
#include <hip/hip_runtime.h>

#define NCTX 4096
#define DMODEL 2048
#define DHEAD 128

typedef _Float16 f16;
typedef f16 f16x8 __attribute__((ext_vector_type(8)));
typedef float f32x4 __attribute__((ext_vector_type(4)));
typedef unsigned short u16;
typedef u16 u16x8 __attribute__((ext_vector_type(8)));

__device__ __forceinline__ u16 f2h(float f) {
  union { f16 h; u16 u; } v; v.h = (f16)f; return v.u;
}
__device__ __forceinline__ float h2f(u16 u) {
  union { u16 u; f16 h; } v; v.u = u; return (float)v.h;
}

__device__ __forceinline__ void gl_lds16(const void* g, void* l) {
  __builtin_amdgcn_global_load_lds((const __attribute__((address_space(1))) void*)g,
                                   (__attribute__((address_space(3))) void*)l, 16, 0, 0);
}

// fp32 -> (hi, lo) f16 split: hi+lo represents x to ~2^-22
__device__ __forceinline__ void splitH4(float4 v, ushort4& h, ushort4& l) {
  h.x = f2h(v.x); l.x = f2h(v.x - h2f(h.x));
  h.y = f2h(v.y); l.y = f2h(v.y - h2f(h.y));
  h.z = f2h(v.z); l.z = f2h(v.z - h2f(h.z));
  h.w = f2h(v.w); l.w = f2h(v.w - h2f(h.w));
}

// ------------- fused prep: x f16-split + f16-transpose | W casts | W2 cast ----------
__global__ __launch_bounds__(256) void prep_all(const float* __restrict__ x,
                                                const float* __restrict__ Wq,
                                                const float* __restrict__ Wk,
                                                const float* __restrict__ W2,
                                                u16* __restrict__ xh, u16* __restrict__ xl,
                                                u16* __restrict__ Wf, u16* __restrict__ W2f,
                                                u16* __restrict__ XT) {
  __shared__ float tile[64][65];
  int b = blockIdx.x;
  int t = threadIdx.x;
  if (b < 2048) {
    int mb = (b >> 5) * 64, db = (b & 31) * 64;
    int tx = t & 15, ty = t >> 4;
#pragma unroll
    for (int rr = 0; rr < 4; ++rr) {
      int row = rr * 16 + ty;
      float4 v = *(const float4*)(x + (size_t)(mb + row) * DMODEL + db + tx * 4);
      ushort4 h, l; splitH4(v, h, l);
      size_t gi = ((size_t)(mb + row) * DMODEL + db) / 4 + tx;
      ((ushort4*)xh)[gi] = h; ((ushort4*)xl)[gi] = l;
      tile[row][tx * 4 + 0] = v.x; tile[row][tx * 4 + 1] = v.y;
      tile[row][tx * 4 + 2] = v.z; tile[row][tx * 4 + 3] = v.w;
    }
    __syncthreads();
#pragma unroll
    for (int rr = 0; rr < 4; ++rr) {
      int r = (t >> 4) * 4 + rr;
      int c0 = (t & 15) * 4;
      ushort4 o;
      o.x = f2h(tile[c0 + 0][r]); o.y = f2h(tile[c0 + 1][r]);
      o.z = f2h(tile[c0 + 2][r]); o.w = f2h(tile[c0 + 3][r]);
      *(ushort4*)(XT + (size_t)(db + r) * NCTX + mb + c0) = o;
    }
  } else if (b < 2560) {               // cast Wq | Wk (single f16)
    int wk = (b >= 2304);
    int i = (b - (wk ? 2304 : 2048)) * 256 + t;
    const float* W = wk ? Wk : Wq;
    size_t off = wk ? ((size_t)DHEAD * DMODEL / 4) : 0;
    float4 v = ((const float4*)W)[i];
    ushort4 o;
    o.x = f2h(v.x); o.y = f2h(v.y); o.z = f2h(v.z); o.w = f2h(v.w);
    ((ushort4*)Wf)[off + i] = o;
  } else {                             // cast W2
    int i = (b - 2560) * 256 + t;
    float4 v = ((const float4*)W2)[i];
    ushort4 o;
    o.x = f2h(v.x); o.y = f2h(v.y); o.z = f2h(v.z); o.w = f2h(v.w);
    ((ushort4*)W2f)[i] = o;
  }
}

// ---------------- 8-way split-K reduce (f16 partials in) -> f16 ----------------
__global__ __launch_bounds__(256) void reduce8h(const u16* __restrict__ P,
                                                u16* __restrict__ out, int n8) {
  int i = blockIdx.x * 256 + threadIdx.x;
  if (i >= n8) return;
  float s[8] = {};
#pragma unroll
  for (int z = 0; z < 8; ++z) {
    u16x8 v = ((const u16x8*)P)[(size_t)z * n8 + i];
#pragma unroll
    for (int k = 0; k < 8; ++k) s[k] += h2f(v[k]);
  }
  u16x8 o;
#pragma unroll
  for (int k = 0; k < 8; ++k) o[k] = f2h(s[k]);
  ((u16x8*)out)[i] = o;
}

// ---------------- causal 2-chunk f16 split-K reduce (rows >= 2048 only) ----------
__global__ __launch_bounds__(256) void reduce_c2(const u16* __restrict__ P,
                                                 u16* __restrict__ out, size_t cs) {
  int row = 2048 + blockIdx.x;
  int t = threadIdx.x;
  size_t base = (size_t)row * DMODEL + t * 8;
  u16x8 a = *(const u16x8*)(P + base);
  u16x8 b = *(const u16x8*)(P + cs + base);
  u16x8 o;
#pragma unroll
  for (int k = 0; k < 8; ++k) o[k] = f2h(h2f(a[k]) + h2f(b[k]));
  *(u16x8*)(out + base) = o;
}

// ---------------- row softmax, one wave per row, f16 S in, balanced pairing ------
// block b: waves handle rows {2b, 2b+1, 4094-2b, 4095-2b} -> uniform ~8.2K work.
__global__ __launch_bounds__(256) void softmax_wave(const u16* __restrict__ S,
                                                    u16* __restrict__ P) {
  int t = threadIdx.x;
  int lane = t & 63, w = t >> 6;
  int b = blockIdx.x;
  int row = (w < 2) ? (2 * b + w) : (4095 - 2 * b - (w - 2));
  const u16* srow = S + (size_t)row * NCTX;
  int len = row + 1;
  int jmax = ((row >> 7) + 1) << 7;  // causal gemm reads j < 128*(bm+1)
  float4 v[16];
  float mx = -3.0e38f;
#pragma unroll
  for (int k = 0; k < 8; ++k) {
    int j = k * 512 + lane * 8;
    if (j < jmax) {
      u16x8 hv = *(const u16x8*)(srow + j);
      float4 a, c;
      a.x = (j + 0 < len) ? h2f(hv[0]) : -3.0e38f;
      a.y = (j + 1 < len) ? h2f(hv[1]) : -3.0e38f;
      a.z = (j + 2 < len) ? h2f(hv[2]) : -3.0e38f;
      a.w = (j + 3 < len) ? h2f(hv[3]) : -3.0e38f;
      c.x = (j + 4 < len) ? h2f(hv[4]) : -3.0e38f;
      c.y = (j + 5 < len) ? h2f(hv[5]) : -3.0e38f;
      c.z = (j + 6 < len) ? h2f(hv[6]) : -3.0e38f;
      c.w = (j + 7 < len) ? h2f(hv[7]) : -3.0e38f;
      v[k * 2] = a; v[k * 2 + 1] = c;
      mx = fmaxf(mx, fmaxf(fmaxf(a.x, a.y), fmaxf(a.z, a.w)));
      mx = fmaxf(mx, fmaxf(fmaxf(c.x, c.y), fmaxf(c.z, c.w)));
    }
  }
#pragma unroll
  for (int o = 32; o > 0; o >>= 1) mx = fmaxf(mx, __shfl_xor(mx, o, 64));
  float sum = 0.f;
#pragma unroll
  for (int k = 0; k < 16; ++k) {
    int j = k * 256 + (lane * 8 & 255) + (k & 1) * 0;  // placeholder, recomputed below
    (void)j;
  }
#pragma unroll
  for (int k = 0; k < 8; ++k) {
    int j = k * 512 + lane * 8;
    if (j < jmax) {
      float4 a = v[k * 2], c = v[k * 2 + 1];
      a.x = (j + 0 < len) ? __expf(a.x - mx) : 0.f;
      a.y = (j + 1 < len) ? __expf(a.y - mx) : 0.f;
      a.z = (j + 2 < len) ? __expf(a.z - mx) : 0.f;
      a.w = (j + 3 < len) ? __expf(a.w - mx) : 0.f;
      c.x = (j + 4 < len) ? __expf(c.x - mx) : 0.f;
      c.y = (j + 5 < len) ? __expf(c.y - mx) : 0.f;
      c.z = (j + 6 < len) ? __expf(c.z - mx) : 0.f;
      c.w = (j + 7 < len) ? __expf(c.w - mx) : 0.f;
      v[k * 2] = a; v[k * 2 + 1] = c;
      sum += a.x + a.y + a.z + a.w + c.x + c.y + c.z + c.w;
    }
  }
#pragma unroll
  for (int o = 32; o > 0; o >>= 1) sum += __shfl_xor(sum, o, 64);
  float inv = 1.0f / sum;
  u16* prow = P + (size_t)row * NCTX;
#pragma unroll
  for (int k = 0; k < 8; ++k) {
    int j = k * 512 + lane * 8;
    if (j < jmax) {
      float4 a = v[k * 2], c = v[k * 2 + 1];
      u16x8 o8;
      o8[0] = f2h(a.x * inv); o8[1] = f2h(a.y * inv);
      o8[2] = f2h(a.z * inv); o8[3] = f2h(a.w * inv);
      o8[4] = f2h(c.x * inv); o8[5] = f2h(c.y * inv);
      o8[6] = f2h(c.z * inv); o8[7] = f2h(c.w * inv);
      *(u16x8*)(prow + j) = o8;
    }
  }
}

// ---------------- scores = q @ k^T, tri-skip grid, K=128, f16 store --------------
// grid (32,32); bm reversed; blocks with bn > bm exit. f16 store to S.
__global__ __launch_bounds__(256, 4) void gemm_scores(const u16* __restrict__ A,
                                                      const u16* __restrict__ B,
                                                      u16* __restrict__ C) {
  int bm = 31 - blockIdx.x, bn = blockIdx.y;
  if (bn > bm) return;
  __shared__ __align__(16) u16 As[128 * 64];
  __shared__ __align__(16) u16 Bs[128 * 64];
  int t = threadIdx.x;
  int lane = t & 63, w = t >> 6;
  int m0 = bm * 128, n0 = bn * 128;
  int wm = (w >> 1) * 64, wn = (w & 1) * 64;
  int mfrag = lane & 15, quad = lane >> 4;
  int srow = t >> 3, schunk = t & 7;
  int rsw = mfrag & 7;
  f32x4 acc[4][4] = {};
#pragma unroll
  for (int kt = 0; kt < 128; kt += 64) {
#pragma unroll
    for (int p = 0; p < 4; ++p) {
      int row = p * 32 + srow;
      int gsc = schunk ^ (row & 7);
      gl_lds16(A + (size_t)(m0 + row) * 256 + kt + gsc * 8, As + (size_t)(p * 256 + t) * 8);
      gl_lds16(B + (size_t)(n0 + row) * 256 + kt + gsc * 8, Bs + (size_t)(p * 256 + t) * 8);
    }
    __syncthreads();
#pragma unroll
    for (int ks = 0; ks < 2; ++ks) {
      int c0 = ((ks * 4 + quad) ^ rsw) * 8;
      f16x8 af[4], bfr[4];
#pragma unroll
      for (int i = 0; i < 4; ++i)
        af[i] = *(const f16x8*)(As + (wm + i * 16 + mfrag) * 64 + c0);
#pragma unroll
      for (int j = 0; j < 4; ++j)
        bfr[j] = *(const f16x8*)(Bs + (wn + j * 16 + mfrag) * 64 + c0);
#pragma unroll
      for (int i = 0; i < 4; ++i)
#pragma unroll
        for (int j = 0; j < 4; ++j)
          acc[i][j] = __builtin_amdgcn_mfma_f32_16x16x32_f16(af[i], bfr[j], acc[i][j], 0, 0, 0);
    }
    __syncthreads();
  }
#pragma unroll
  for (int i = 0; i < 4; ++i)
#pragma unroll
    for (int j = 0; j < 4; ++j)
#pragma unroll
      for (int rr = 0; rr < 4; ++rr) {
        int row = m0 + wm + i * 16 + quad * 4 + rr;
        int col = n0 + wn + j * 16 + mfrag;
        C[(size_t)row * NCTX + col] = f2h(acc[i][j][rr]);
      }
}

// ---------------- qk projection as virtual K=4096 concat GEMM -------------------
// q,k = xh@W^T + xl@W^T. Chunk kc<4 reads xh, kc>=4 reads xl (KC=512 | 2048).
__global__ __launch_bounds__(256, 4) void gemm_qk(const u16* __restrict__ Ah,
                                                  const u16* __restrict__ Al,
                                                  const u16* __restrict__ B,
                                                  u16* __restrict__ C) {
  int bm = blockIdx.x, bn = blockIdx.y, kc = blockIdx.z;
  const u16* A = (kc < 4) ? Ah : Al;
  int kStart = (kc & 3) * 512;
  int kStop = kStart + 512;
  __shared__ __align__(16) u16 As[128 * 64];
  __shared__ __align__(16) u16 Bs[128 * 64];
  int t = threadIdx.x;
  int lane = t & 63, w = t >> 6;
  int m0 = bm * 128, n0 = bn * 128;
  int wm = (w >> 1) * 64, wn = (w & 1) * 64;
  int mfrag = lane & 15, quad = lane >> 4;
  int srow = t >> 3, schunk = t & 7;
  int rsw = mfrag & 7;
  f32x4 acc[4][4] = {};
  for (int kt = kStart; kt < kStop; kt += 64) {
#pragma unroll
    for (int p = 0; p < 4; ++p) {
      int row = p * 32 + srow;
      int gsc = schunk ^ (row & 7);
      gl_lds16(A + (size_t)(m0 + row) * DMODEL + kt + gsc * 8, As + (size_t)(p * 256 + t) * 8);
      gl_lds16(B + (size_t)(n0 + row) * DMODEL + kt + gsc * 8, Bs + (size_t)(p * 256 + t) * 8);
    }
    __syncthreads();
#pragma unroll
    for (int ks = 0; ks < 2; ++ks) {
      int c0 = ((ks * 4 + quad) ^ rsw) * 8;
      f16x8 af[4], bfr[4];
#pragma unroll
      for (int i = 0; i < 4; ++i)
        af[i] = *(const f16x8*)(As + (wm + i * 16 + mfrag) * 64 + c0);
#pragma unroll
      for (int j = 0; j < 4; ++j)
        bfr[j] = *(const f16x8*)(Bs + (wn + j * 16 + mfrag) * 64 + c0);
#pragma unroll
      for (int i = 0; i < 4; ++i)
#pragma unroll
        for (int j = 0; j < 4; ++j)
          acc[i][j] = __builtin_amdgcn_mfma_f32_16x16x32_f16(af[i], bfr[j], acc[i][j], 0, 0, 0);
    }
    __syncthreads();
  }
  u16* Cc = C + (size_t)kc * ((size_t)NCTX * 256);
#pragma unroll
  for (int i = 0; i < 4; ++i)
#pragma unroll
    for (int j = 0; j < 4; ++j)
#pragma unroll
      for (int rr = 0; rr < 4; ++rr) {
        int row = m0 + wm + i * 16 + quad * 4 + rr;
        int col = n0 + wn + j * 16 + mfrag;
        Cc[(size_t)row * 256 + col] = f2h(acc[i][j][rr]);
      }
}

// ---------------- f16 MFMA GEMM, B^T, 128x128, BK=64, XOR swizzle, fp32 out -------
// out@W2: z=1, K=2048 unsplit, direct fp32 store to d_out.
__global__ __launch_bounds__(256, 4) void gemm_f16_p(const u16* __restrict__ A,
                                                     const u16* __restrict__ B,
                                                     float* __restrict__ C,
                                                     int lda, int ldb, int ldc,
                                                     int K) {
  int bm = blockIdx.x, bn = blockIdx.y;
  __shared__ __align__(16) u16 As[128 * 64];
  __shared__ __align__(16) u16 Bs[128 * 64];
  int t = threadIdx.x;
  int lane = t & 63, w = t >> 6;
  int m0 = bm * 128, n0 = bn * 128;
  int wm = (w >> 1) * 64, wn = (w & 1) * 64;
  int mfrag = lane & 15, quad = lane >> 4;
  int srow = t >> 3, schunk = t & 7;
  int rsw = mfrag & 7;
  f32x4 acc[4][4] = {};
  for (int kt = 0; kt < K; kt += 64) {
#pragma unroll
    for (int p = 0; p < 4; ++p) {
      int row = p * 32 + srow;
      int gsc = schunk ^ (row & 7);
      gl_lds16(A + (size_t)(m0 + row) * lda + kt + gsc * 8, As + (size_t)(p * 256 + t) * 8);
      gl_lds16(B + (size_t)(n0 + row) * ldb + kt + gsc * 8, Bs + (size_t)(p * 256 + t) * 8);
    }
    __syncthreads();
#pragma unroll
    for (int ks = 0; ks < 2; ++ks) {
      int c0 = ((ks * 4 + quad) ^ rsw) * 8;
      f16x8 af[4], bfr[4];
#pragma unroll
      for (int i = 0; i < 4; ++i)
        af[i] = *(const f16x8*)(As + (wm + i * 16 + mfrag) * 64 + c0);
#pragma unroll
      for (int j = 0; j < 4; ++j)
        bfr[j] = *(const f16x8*)(Bs + (wn + j * 16 + mfrag) * 64 + c0);
#pragma unroll
      for (int i = 0; i < 4; ++i)
#pragma unroll
        for (int j = 0; j < 4; ++j)
          acc[i][j] = __builtin_amdgcn_mfma_f32_16x16x32_f16(af[i], bfr[j], acc[i][j], 0, 0, 0);
    }
    __syncthreads();
  }
#pragma unroll
  for (int i = 0; i < 4; ++i)
#pragma unroll
    for (int j = 0; j < 4; ++j)
#pragma unroll
      for (int rr = 0; rr < 4; ++rr) {
        int row = m0 + wm + i * 16 + quad * 4 + rr;
        int col = n0 + wn + j * 16 + mfrag;
        C[(size_t)row * ldc + col] = acc[i][j][rr];
      }
}

// ---------------- attn@x causal GEMM: packed, size-balanced 1D grid --------------
__global__ __launch_bounds__(256, 4) void gemm_attnx(const u16* __restrict__ A,
                                                     const u16* __restrict__ B,
                                                     u16* __restrict__ C,
                                                     u16* __restrict__ Cf,
                                                     size_t chunkStride) {
  int b = blockIdx.x;
  int s = b >> 8, c = b & 255;
  int r = (s == 0) ? c : (s == 1) ? (511 - c) : (512 + c);
  int bm, bn, kc;
  if (r < 272) {
    bm = 15 + (r >> 4); bn = r & 15; kc = 0;
  } else if (r < 288) {
    bm = 31; bn = r - 272; kc = 1;
  } else {
    int g = (r - 288) >> 5, j = (r - 288) & 31;
    int k = 15 - g;
    if (j < 16) { bm = k - 1; bn = j; kc = 0; }
    else        { bm = 15 + k; bn = j - 16; kc = 1; }
  }
  int kEnd = (bm + 1) * 128;
  if (kEnd > NCTX) kEnd = NCTX;
  int kStart = kc * 2048;
  int kStop = kStart + 2048 < kEnd ? kStart + 2048 : kEnd;
  __shared__ __align__(16) u16 As[128 * 64];
  __shared__ __align__(16) u16 Bs[128 * 64];
  int t = threadIdx.x;
  int lane = t & 63, w = t >> 6;
  int m0 = bm * 128, n0 = bn * 128;
  int wm = (w >> 1) * 64, wn = (w & 1) * 64;
  int mfrag = lane & 15, quad = lane >> 4;
  int srow = t >> 3, schunk = t & 7;
  int rsw = mfrag & 7;
  f32x4 acc[4][4] = {};
  for (int kt = kStart; kt < kStop; kt += 64) {
#pragma unroll
    for (int p = 0; p < 4; ++p) {
      int row = p * 32 + srow;
      int gsc = schunk ^ (row & 7);
      gl_lds16(A + (size_t)(m0 + row) * NCTX + kt + gsc * 8, As + (size_t)(p * 256 + t) * 8);
      gl_lds16(B + (size_t)(n0 + row) * NCTX + kt + gsc * 8, Bs + (size_t)(p * 256 + t) * 8);
    }
    __syncthreads();
#pragma unroll
    for (int ks = 0; ks < 2; ++ks) {
      int c0 = ((ks * 4 + quad) ^ rsw) * 8;
      f16x8 af[4], bfr[4];
#pragma unroll
      for (int i = 0; i < 4; ++i)
        af[i] = *(const f16x8*)(As + (wm + i * 16 + mfrag) * 64 + c0);
#pragma unroll
      for (int j = 0; j < 4; ++j)
        bfr[j] = *(const f16x8*)(Bs + (wn + j * 16 + mfrag) * 64 + c0);
#pragma unroll
      for (int i = 0; i < 4; ++i)
#pragma unroll
        for (int j = 0; j < 4; ++j)
          acc[i][j] = __builtin_amdgcn_mfma_f32_16x16x32_f16(af[i], bfr[j], acc[i][j], 0, 0, 0);
    }
    __syncthreads();
  }
  // bm<16: chunk covers whole causal K -> final-direct to Cf; else f16 partial.
  u16* Cc = (kc == 0 && kEnd <= 2048) ? Cf : (C + (size_t)kc * chunkStride);
#pragma unroll
  for (int i = 0; i < 4; ++i)
#pragma unroll
    for (int j = 0; j < 4; ++j)
#pragma unroll
      for (int rr = 0; rr < 4; ++rr) {
        int row = m0 + wm + i * 16 + quad * 4 + rr;
        int col = n0 + wn + j * 16 + mfrag;
        Cc[(size_t)row * DMODEL + col] = f2h(acc[i][j][rr]);
      }
}

extern "C" void kernel_launch(void* const* d_in, const int* in_sizes, int n_in,
                              void* d_out, int out_size, void* d_ws, size_t ws_size,
                              hipStream_t stream) {
  const float* x  = (const float*)d_in[0];
  const float* Wk = (const float*)d_in[1];
  const float* Wq = (const float*)d_in[2];
  const float* W2 = (const float*)d_in[3];

  char* ws = (char*)d_ws;
  const size_t MB = 1024 * 1024;
  // persistent region [0, 75 MB)
  u16*   QKf  = (u16*)  (ws + 0);            //  2 MB  [4096,256] f16 (q | k)
  u16*   Wf   = (u16*)  (ws + 2 * MB);       //  1 MB  [256,2048] (Wq ; Wk) f16
  u16*   xT   = (u16*)  (ws + 3 * MB);       // 16 MB  [2048,4096] f16
  u16*   W2f  = (u16*)  (ws + 19 * MB);      //  8 MB  [2048,2048] f16
  u16*   outb = (u16*)  (ws + 27 * MB);      // 16 MB  [4096,2048] f16
  u16*   attn = (u16*)  (ws + 43 * MB);      // 32 MB  [4096,4096] f16
  // reusable region A [75, 139 MB) — lifetimes strictly sequential:
  u16*   xh   = (u16*)  (ws + 75 * MB);      // 16 MB  (dead after qk gemm)
  u16*   xl   = (u16*)  (ws + 91 * MB);      // 16 MB  (dead after qk gemm)
  u16*   QKp  = (u16*)  (ws + 107 * MB);     // 16 MB  8 x [4096,256] f16 partials
  u16*   S16  = (u16*)  (ws + 75 * MB);      // 32 MB  f16 scores (after xh/xl/QKp dead)
  u16*   Ph   = (u16*)  (ws + 75 * MB);      // 32 MB  2 x [4096,2048] f16 partials (after S16 dead)

  const int QKN8 = NCTX * 256 / 8;
  const size_t CS = (size_t)NCTX * DMODEL;   // partial chunk stride (elements)

  // fused prep: x f16-split + f16 transpose + W/W2 casts
  prep_all<<<6656, 256, 0, stream>>>(x, Wq, Wk, W2, xh, xl, Wf, W2f, xT);

  // q,k: virtual K=4096 concat (xh | xl) @ Wf^T, 8 f16-partial chunks KC=512
  gemm_qk<<<dim3(NCTX / 128, 2, 8), 256, 0, stream>>>(xh, xl, Wf, QKp);
  reduce8h<<<(QKN8 + 255) / 256, 256, 0, stream>>>(QKp, QKf, QKN8);

  // scores = q @ k^T, tri-skip grid, f16 store
  gemm_scores<<<dim3(32, 32), 256, 0, stream>>>(QKf, QKf + DHEAD, S16);
  softmax_wave<<<1024, 256, 0, stream>>>(S16, attn);

  // out = attn @ x (causal): packed 768-block balanced grid; rows<2048
  // final-direct to outb, rows>=2048 f16 partials -> reduce_c2
  gemm_attnx<<<768, 256, 0, stream>>>(attn, xT, Ph, outb, CS);
  reduce_c2<<<2048, 256, 0, stream>>>(Ph, outb, CS);

  // final = out @ W2^T: z=1, K=2048 unsplit, direct fp32 store to d_out
  gemm_f16_p<<<dim3(NCTX / 128, DMODEL / 128), 256, 0, stream>>>(
      outb, W2f, (float*)d_out, DMODEL, DMODEL, DMODEL, DMODEL);
}

// Round 10
// 221.514 us; speedup vs baseline: 1.0329x; 1.0329x over previous
//
#include <hip/hip_runtime.h>

#define NCTX 4096
#define DMODEL 2048
#define DHEAD 128

typedef _Float16 f16;
typedef f16 f16x8 __attribute__((ext_vector_type(8)));
typedef float f32x4 __attribute__((ext_vector_type(4)));
typedef unsigned short u16;
typedef u16 u16x8 __attribute__((ext_vector_type(8)));

__device__ __forceinline__ u16 f2h(float f) {
  union { f16 h; u16 u; } v; v.h = (f16)f; return v.u;
}
__device__ __forceinline__ float h2f(u16 u) {
  union { u16 u; f16 h; } v; v.u = u; return (float)v.h;
}

__device__ __forceinline__ void gl_lds16(const void* g, void* l) {
  __builtin_amdgcn_global_load_lds((const __attribute__((address_space(1))) void*)g,
                                   (__attribute__((address_space(3))) void*)l, 16, 0, 0);
}

// ------------- fused prep: x f16 cast + f16-transpose | W casts | W2 cast ----------
__global__ __launch_bounds__(256) void prep_all(const float* __restrict__ x,
                                                const float* __restrict__ Wq,
                                                const float* __restrict__ Wk,
                                                const float* __restrict__ W2,
                                                u16* __restrict__ xf,
                                                u16* __restrict__ Wf, u16* __restrict__ W2f,
                                                u16* __restrict__ XT) {
  __shared__ float tile[64][65];
  int b = blockIdx.x;
  int t = threadIdx.x;
  if (b < 2048) {
    int mb = (b >> 5) * 64, db = (b & 31) * 64;
    int tx = t & 15, ty = t >> 4;
#pragma unroll
    for (int rr = 0; rr < 4; ++rr) {
      int row = rr * 16 + ty;
      float4 v = *(const float4*)(x + (size_t)(mb + row) * DMODEL + db + tx * 4);
      ushort4 h;
      h.x = f2h(v.x); h.y = f2h(v.y); h.z = f2h(v.z); h.w = f2h(v.w);
      size_t gi = ((size_t)(mb + row) * DMODEL + db) / 4 + tx;
      ((ushort4*)xf)[gi] = h;
      tile[row][tx * 4 + 0] = v.x; tile[row][tx * 4 + 1] = v.y;
      tile[row][tx * 4 + 2] = v.z; tile[row][tx * 4 + 3] = v.w;
    }
    __syncthreads();
#pragma unroll
    for (int rr = 0; rr < 4; ++rr) {
      int r = (t >> 4) * 4 + rr;
      int c0 = (t & 15) * 4;
      ushort4 o;
      o.x = f2h(tile[c0 + 0][r]); o.y = f2h(tile[c0 + 1][r]);
      o.z = f2h(tile[c0 + 2][r]); o.w = f2h(tile[c0 + 3][r]);
      *(ushort4*)(XT + (size_t)(db + r) * NCTX + mb + c0) = o;
    }
  } else if (b < 2560) {               // cast Wq | Wk (single f16)
    int wk = (b >= 2304);
    int i = (b - (wk ? 2304 : 2048)) * 256 + t;
    const float* W = wk ? Wk : Wq;
    size_t off = wk ? ((size_t)DHEAD * DMODEL / 4) : 0;
    float4 v = ((const float4*)W)[i];
    ushort4 o;
    o.x = f2h(v.x); o.y = f2h(v.y); o.z = f2h(v.z); o.w = f2h(v.w);
    ((ushort4*)Wf)[off + i] = o;
  } else {                             // cast W2
    int i = (b - 2560) * 256 + t;
    float4 v = ((const float4*)W2)[i];
    ushort4 o;
    o.x = f2h(v.x); o.y = f2h(v.y); o.z = f2h(v.z); o.w = f2h(v.w);
    ((ushort4*)W2f)[i] = o;
  }
}

// ---------------- 8-way split-K reduce (f16 partials in) -> f16 ----------------
__global__ __launch_bounds__(256) void reduce8h(const u16* __restrict__ P,
                                                u16* __restrict__ out, int n8) {
  int i = blockIdx.x * 256 + threadIdx.x;
  if (i >= n8) return;
  float s[8] = {};
#pragma unroll
  for (int z = 0; z < 8; ++z) {
    u16x8 v = ((const u16x8*)P)[(size_t)z * n8 + i];
#pragma unroll
    for (int k = 0; k < 8; ++k) s[k] += h2f(v[k]);
  }
  u16x8 o;
#pragma unroll
  for (int k = 0; k < 8; ++k) o[k] = f2h(s[k]);
  ((u16x8*)out)[i] = o;
}

// ---------------- causal 2-chunk f16 split-K reduce (rows >= 2048 only) ----------
__global__ __launch_bounds__(256) void reduce_c2(const u16* __restrict__ P,
                                                 u16* __restrict__ out, size_t cs) {
  int row = 2048 + blockIdx.x;
  int t = threadIdx.x;
  size_t base = (size_t)row * DMODEL + t * 8;
  u16x8 a = *(const u16x8*)(P + base);
  u16x8 b = *(const u16x8*)(P + cs + base);
  u16x8 o;
#pragma unroll
  for (int k = 0; k < 8; ++k) o[k] = f2h(h2f(a[k]) + h2f(b[k]));
  *(u16x8*)(out + base) = o;
}

// ---------------- row softmax, one wave per row (fp32 S), balanced pairing -------
// block b: waves handle rows {2b, 2b+1, 4094-2b, 4095-2b} -> uniform work/block.
__global__ __launch_bounds__(256) void softmax_wave(const float* __restrict__ S,
                                                    u16* __restrict__ P) {
  int t = threadIdx.x;
  int lane = t & 63, w = t >> 6;
  int b = blockIdx.x;
  int row = (w < 2) ? (2 * b + w) : (4095 - 2 * b - (w - 2));
  const float* srow = S + (size_t)row * NCTX;
  int len = row + 1;
  int jmax = ((row >> 7) + 1) << 7;  // causal gemm reads j < 128*(bm+1)
  float4 v[16];
  float mx = -3.0e38f;
#pragma unroll
  for (int k = 0; k < 16; ++k) {
    int j = k * 256 + lane * 4;
    if (j < jmax) {
      float4 x = *(const float4*)(srow + j);
      x.x = (j + 0 < len) ? x.x : -3.0e38f;
      x.y = (j + 1 < len) ? x.y : -3.0e38f;
      x.z = (j + 2 < len) ? x.z : -3.0e38f;
      x.w = (j + 3 < len) ? x.w : -3.0e38f;
      v[k] = x;
      mx = fmaxf(mx, fmaxf(fmaxf(x.x, x.y), fmaxf(x.z, x.w)));
    }
  }
#pragma unroll
  for (int o = 32; o > 0; o >>= 1) mx = fmaxf(mx, __shfl_xor(mx, o, 64));
  float sum = 0.f;
#pragma unroll
  for (int k = 0; k < 16; ++k) {
    int j = k * 256 + lane * 4;
    if (j < jmax) {
      float4 x = v[k];
      x.x = (j + 0 < len) ? __expf(x.x - mx) : 0.f;
      x.y = (j + 1 < len) ? __expf(x.y - mx) : 0.f;
      x.z = (j + 2 < len) ? __expf(x.z - mx) : 0.f;
      x.w = (j + 3 < len) ? __expf(x.w - mx) : 0.f;
      v[k] = x;
      sum += x.x + x.y + x.z + x.w;
    }
  }
#pragma unroll
  for (int o = 32; o > 0; o >>= 1) sum += __shfl_xor(sum, o, 64);
  float inv = 1.0f / sum;
  u16* prow = P + (size_t)row * NCTX;
#pragma unroll
  for (int k = 0; k < 16; ++k) {
    int j = k * 256 + lane * 4;
    if (j < jmax) {
      float4 x = v[k];
      ushort4 o4;
      o4.x = f2h(x.x * inv); o4.y = f2h(x.y * inv);
      o4.z = f2h(x.z * inv); o4.w = f2h(x.w * inv);
      *(ushort4*)(prow + j) = o4;
    }
  }
}

// ---------------- scores = q @ k^T, tri-skip grid, K=128, fp32 store -------------
// grid (32,32); bm reversed; blocks with bn > bm exit.
__global__ __launch_bounds__(256, 4) void gemm_scores(const u16* __restrict__ A,
                                                      const u16* __restrict__ B,
                                                      float* __restrict__ C) {
  int bm = 31 - blockIdx.x, bn = blockIdx.y;
  if (bn > bm) return;
  __shared__ __align__(16) u16 As[128 * 64];
  __shared__ __align__(16) u16 Bs[128 * 64];
  int t = threadIdx.x;
  int lane = t & 63, w = t >> 6;
  int m0 = bm * 128, n0 = bn * 128;
  int wm = (w >> 1) * 64, wn = (w & 1) * 64;
  int mfrag = lane & 15, quad = lane >> 4;
  int srow = t >> 3, schunk = t & 7;
  int rsw = mfrag & 7;
  f32x4 acc[4][4] = {};
#pragma unroll
  for (int kt = 0; kt < 128; kt += 64) {
#pragma unroll
    for (int p = 0; p < 4; ++p) {
      int row = p * 32 + srow;
      int gsc = schunk ^ (row & 7);
      gl_lds16(A + (size_t)(m0 + row) * 256 + kt + gsc * 8, As + (size_t)(p * 256 + t) * 8);
      gl_lds16(B + (size_t)(n0 + row) * 256 + kt + gsc * 8, Bs + (size_t)(p * 256 + t) * 8);
    }
    __syncthreads();
#pragma unroll
    for (int ks = 0; ks < 2; ++ks) {
      int c0 = ((ks * 4 + quad) ^ rsw) * 8;
      f16x8 af[4], bfr[4];
#pragma unroll
      for (int i = 0; i < 4; ++i)
        af[i] = *(const f16x8*)(As + (wm + i * 16 + mfrag) * 64 + c0);
#pragma unroll
      for (int j = 0; j < 4; ++j)
        bfr[j] = *(const f16x8*)(Bs + (wn + j * 16 + mfrag) * 64 + c0);
#pragma unroll
      for (int i = 0; i < 4; ++i)
#pragma unroll
        for (int j = 0; j < 4; ++j)
          acc[i][j] = __builtin_amdgcn_mfma_f32_16x16x32_f16(af[i], bfr[j], acc[i][j], 0, 0, 0);
    }
    __syncthreads();
  }
#pragma unroll
  for (int i = 0; i < 4; ++i)
#pragma unroll
    for (int j = 0; j < 4; ++j)
#pragma unroll
      for (int rr = 0; rr < 4; ++rr) {
        int row = m0 + wm + i * 16 + quad * 4 + rr;
        int col = n0 + wn + j * 16 + mfrag;
        C[(size_t)row * NCTX + col] = acc[i][j][rr];
      }
}

// ---------------- qk projection, single-f16 x, split-K z=8 KC=256 ----------------
// q,k = xf @ Wf^T; 8 f16-partial chunks (layout matches reduce8h).
__global__ __launch_bounds__(256, 4) void gemm_qk(const u16* __restrict__ A,
                                                  const u16* __restrict__ B,
                                                  u16* __restrict__ C) {
  int bm = blockIdx.x, bn = blockIdx.y, kc = blockIdx.z;
  int kStart = kc * 256;
  int kStop = kStart + 256;
  __shared__ __align__(16) u16 As[128 * 64];
  __shared__ __align__(16) u16 Bs[128 * 64];
  int t = threadIdx.x;
  int lane = t & 63, w = t >> 6;
  int m0 = bm * 128, n0 = bn * 128;
  int wm = (w >> 1) * 64, wn = (w & 1) * 64;
  int mfrag = lane & 15, quad = lane >> 4;
  int srow = t >> 3, schunk = t & 7;
  int rsw = mfrag & 7;
  f32x4 acc[4][4] = {};
  for (int kt = kStart; kt < kStop; kt += 64) {
#pragma unroll
    for (int p = 0; p < 4; ++p) {
      int row = p * 32 + srow;
      int gsc = schunk ^ (row & 7);
      gl_lds16(A + (size_t)(m0 + row) * DMODEL + kt + gsc * 8, As + (size_t)(p * 256 + t) * 8);
      gl_lds16(B + (size_t)(n0 + row) * DMODEL + kt + gsc * 8, Bs + (size_t)(p * 256 + t) * 8);
    }
    __syncthreads();
#pragma unroll
    for (int ks = 0; ks < 2; ++ks) {
      int c0 = ((ks * 4 + quad) ^ rsw) * 8;
      f16x8 af[4], bfr[4];
#pragma unroll
      for (int i = 0; i < 4; ++i)
        af[i] = *(const f16x8*)(As + (wm + i * 16 + mfrag) * 64 + c0);
#pragma unroll
      for (int j = 0; j < 4; ++j)
        bfr[j] = *(const f16x8*)(Bs + (wn + j * 16 + mfrag) * 64 + c0);
#pragma unroll
      for (int i = 0; i < 4; ++i)
#pragma unroll
        for (int j = 0; j < 4; ++j)
          acc[i][j] = __builtin_amdgcn_mfma_f32_16x16x32_f16(af[i], bfr[j], acc[i][j], 0, 0, 0);
    }
    __syncthreads();
  }
  u16* Cc = C + (size_t)kc * ((size_t)NCTX * 256);
#pragma unroll
  for (int i = 0; i < 4; ++i)
#pragma unroll
    for (int j = 0; j < 4; ++j)
#pragma unroll
      for (int rr = 0; rr < 4; ++rr) {
        int row = m0 + wm + i * 16 + quad * 4 + rr;
        int col = n0 + wn + j * 16 + mfrag;
        Cc[(size_t)row * 256 + col] = f2h(acc[i][j][rr]);
      }
}

// ---------------- f16 MFMA GEMM, B^T, 128x128, BK=64, XOR swizzle, fp32 out -------
// out@W2: z=1, K=2048 unsplit, direct fp32 store to d_out.
__global__ __launch_bounds__(256, 4) void gemm_f16_p(const u16* __restrict__ A,
                                                     const u16* __restrict__ B,
                                                     float* __restrict__ C,
                                                     int lda, int ldb, int ldc,
                                                     int K) {
  int bm = blockIdx.x, bn = blockIdx.y;
  __shared__ __align__(16) u16 As[128 * 64];
  __shared__ __align__(16) u16 Bs[128 * 64];
  int t = threadIdx.x;
  int lane = t & 63, w = t >> 6;
  int m0 = bm * 128, n0 = bn * 128;
  int wm = (w >> 1) * 64, wn = (w & 1) * 64;
  int mfrag = lane & 15, quad = lane >> 4;
  int srow = t >> 3, schunk = t & 7;
  int rsw = mfrag & 7;
  f32x4 acc[4][4] = {};
  for (int kt = 0; kt < K; kt += 64) {
#pragma unroll
    for (int p = 0; p < 4; ++p) {
      int row = p * 32 + srow;
      int gsc = schunk ^ (row & 7);
      gl_lds16(A + (size_t)(m0 + row) * lda + kt + gsc * 8, As + (size_t)(p * 256 + t) * 8);
      gl_lds16(B + (size_t)(n0 + row) * ldb + kt + gsc * 8, Bs + (size_t)(p * 256 + t) * 8);
    }
    __syncthreads();
#pragma unroll
    for (int ks = 0; ks < 2; ++ks) {
      int c0 = ((ks * 4 + quad) ^ rsw) * 8;
      f16x8 af[4], bfr[4];
#pragma unroll
      for (int i = 0; i < 4; ++i)
        af[i] = *(const f16x8*)(As + (wm + i * 16 + mfrag) * 64 + c0);
#pragma unroll
      for (int j = 0; j < 4; ++j)
        bfr[j] = *(const f16x8*)(Bs + (wn + j * 16 + mfrag) * 64 + c0);
#pragma unroll
      for (int i = 0; i < 4; ++i)
#pragma unroll
        for (int j = 0; j < 4; ++j)
          acc[i][j] = __builtin_amdgcn_mfma_f32_16x16x32_f16(af[i], bfr[j], acc[i][j], 0, 0, 0);
    }
    __syncthreads();
  }
#pragma unroll
  for (int i = 0; i < 4; ++i)
#pragma unroll
    for (int j = 0; j < 4; ++j)
#pragma unroll
      for (int rr = 0; rr < 4; ++rr) {
        int row = m0 + wm + i * 16 + quad * 4 + rr;
        int col = n0 + wn + j * 16 + mfrag;
        C[(size_t)row * ldc + col] = acc[i][j][rr];
      }
}

// ---------------- attn@x causal GEMM: packed, size-balanced 1D grid --------------
__global__ __launch_bounds__(256, 4) void gemm_attnx(const u16* __restrict__ A,
                                                     const u16* __restrict__ B,
                                                     u16* __restrict__ C,
                                                     u16* __restrict__ Cf,
                                                     size_t chunkStride) {
  int b = blockIdx.x;
  int s = b >> 8, c = b & 255;
  int r = (s == 0) ? c : (s == 1) ? (511 - c) : (512 + c);
  int bm, bn, kc;
  if (r < 272) {
    bm = 15 + (r >> 4); bn = r & 15; kc = 0;
  } else if (r < 288) {
    bm = 31; bn = r - 272; kc = 1;
  } else {
    int g = (r - 288) >> 5, j = (r - 288) & 31;
    int k = 15 - g;
    if (j < 16) { bm = k - 1; bn = j; kc = 0; }
    else        { bm = 15 + k; bn = j - 16; kc = 1; }
  }
  int kEnd = (bm + 1) * 128;
  if (kEnd > NCTX) kEnd = NCTX;
  int kStart = kc * 2048;
  int kStop = kStart + 2048 < kEnd ? kStart + 2048 : kEnd;
  __shared__ __align__(16) u16 As[128 * 64];
  __shared__ __align__(16) u16 Bs[128 * 64];
  int t = threadIdx.x;
  int lane = t & 63, w = t >> 6;
  int m0 = bm * 128, n0 = bn * 128;
  int wm = (w >> 1) * 64, wn = (w & 1) * 64;
  int mfrag = lane & 15, quad = lane >> 4;
  int srow = t >> 3, schunk = t & 7;
  int rsw = mfrag & 7;
  f32x4 acc[4][4] = {};
  for (int kt = kStart; kt < kStop; kt += 64) {
#pragma unroll
    for (int p = 0; p < 4; ++p) {
      int row = p * 32 + srow;
      int gsc = schunk ^ (row & 7);
      gl_lds16(A + (size_t)(m0 + row) * NCTX + kt + gsc * 8, As + (size_t)(p * 256 + t) * 8);
      gl_lds16(B + (size_t)(n0 + row) * NCTX + kt + gsc * 8, Bs + (size_t)(p * 256 + t) * 8);
    }
    __syncthreads();
#pragma unroll
    for (int ks = 0; ks < 2; ++ks) {
      int c0 = ((ks * 4 + quad) ^ rsw) * 8;
      f16x8 af[4], bfr[4];
#pragma unroll
      for (int i = 0; i < 4; ++i)
        af[i] = *(const f16x8*)(As + (wm + i * 16 + mfrag) * 64 + c0);
#pragma unroll
      for (int j = 0; j < 4; ++j)
        bfr[j] = *(const f16x8*)(Bs + (wn + j * 16 + mfrag) * 64 + c0);
#pragma unroll
      for (int i = 0; i < 4; ++i)
#pragma unroll
        for (int j = 0; j < 4; ++j)
          acc[i][j] = __builtin_amdgcn_mfma_f32_16x16x32_f16(af[i], bfr[j], acc[i][j], 0, 0, 0);
    }
    __syncthreads();
  }
  // bm<16: chunk covers whole causal K -> final-direct to Cf; else f16 partial.
  u16* Cc = (kc == 0 && kEnd <= 2048) ? Cf : (C + (size_t)kc * chunkStride);
#pragma unroll
  for (int i = 0; i < 4; ++i)
#pragma unroll
    for (int j = 0; j < 4; ++j)
#pragma unroll
      for (int rr = 0; rr < 4; ++rr) {
        int row = m0 + wm + i * 16 + quad * 4 + rr;
        int col = n0 + wn + j * 16 + mfrag;
        Cc[(size_t)row * DMODEL + col] = f2h(acc[i][j][rr]);
      }
}

extern "C" void kernel_launch(void* const* d_in, const int* in_sizes, int n_in,
                              void* d_out, int out_size, void* d_ws, size_t ws_size,
                              hipStream_t stream) {
  const float* x  = (const float*)d_in[0];
  const float* Wk = (const float*)d_in[1];
  const float* Wq = (const float*)d_in[2];
  const float* W2 = (const float*)d_in[3];

  char* ws = (char*)d_ws;
  const size_t MB = 1024 * 1024;
  // persistent region [0, 75 MB)
  u16*   QKf  = (u16*)  (ws + 0);            //  2 MB  [4096,256] f16 (q | k)
  u16*   Wf   = (u16*)  (ws + 2 * MB);       //  1 MB  [256,2048] (Wq ; Wk) f16
  u16*   xT   = (u16*)  (ws + 3 * MB);       // 16 MB  [2048,4096] f16
  u16*   W2f  = (u16*)  (ws + 19 * MB);      //  8 MB  [2048,2048] f16
  u16*   outb = (u16*)  (ws + 27 * MB);      // 16 MB  [4096,2048] f16
  u16*   attn = (u16*)  (ws + 43 * MB);      // 32 MB  [4096,4096] f16
  // reusable region A [75, 139 MB) — lifetimes strictly sequential:
  u16*   xf   = (u16*)  (ws + 75 * MB);      // 16 MB  f16 x (dead after qk gemm)
  u16*   QKp  = (u16*)  (ws + 107 * MB);     // 16 MB  8 x [4096,256] f16 partials
  float* S    = (float*)(ws + 75 * MB);      // 64 MB  fp32 scores (after xf/QKp dead)
  u16*   Ph   = (u16*)  (ws + 75 * MB);      // 32 MB  2 x [4096,2048] f16 partials (after S dead)

  const int QKN8 = NCTX * 256 / 8;
  const size_t CS = (size_t)NCTX * DMODEL;   // partial chunk stride (elements)

  // fused prep: x f16 cast + f16 transpose + W/W2 casts
  prep_all<<<6656, 256, 0, stream>>>(x, Wq, Wk, W2, xf, Wf, W2f, xT);

  // q,k = xf @ Wf^T, split-K z=8 KC=256, f16 partials
  gemm_qk<<<dim3(NCTX / 128, 2, 8), 256, 0, stream>>>(xf, Wf, QKp);
  reduce8h<<<(QKN8 + 255) / 256, 256, 0, stream>>>(QKp, QKf, QKN8);

  // scores = q @ k^T, tri-skip grid, fp32 store
  gemm_scores<<<dim3(32, 32), 256, 0, stream>>>(QKf, QKf + DHEAD, S);
  softmax_wave<<<1024, 256, 0, stream>>>(S, attn);

  // out = attn @ x (causal): packed 768-block balanced grid; rows<2048
  // final-direct to outb, rows>=2048 f16 partials -> reduce_c2
  gemm_attnx<<<768, 256, 0, stream>>>(attn, xT, Ph, outb, CS);
  reduce_c2<<<2048, 256, 0, stream>>>(Ph, outb, CS);

  // final = out @ W2^T: z=1, K=2048 unsplit, direct fp32 store to d_out
  gemm_f16_p<<<dim3(NCTX / 128, DMODEL / 128), 256, 0, stream>>>(
      outb, W2f, (float*)d_out, DMODEL, DMODEL, DMODEL, DMODEL);
}